// Round 4
// baseline (566.562 us; speedup 1.0000x reference)
//
#include <hip/hip_runtime.h>
#include <stdint.h>

// Problem constants
#define NIMG   32
#define CCH    256
#define WDIM   56
#define HW     3136          // 56*56
#define MTOT   (NIMG*HW)     // 100352
#define KCTOT  36            // 4 ci-chunks * 9 taps
#define BK     64

typedef __attribute__((ext_vector_type(8))) short    bf16x8;
typedef __attribute__((ext_vector_type(4))) float    f32x4;
typedef __attribute__((ext_vector_type(4))) uint32_t u32x4;

typedef __attribute__((address_space(1))) const uint8_t* as1cp;
typedef __attribute__((address_space(3))) uint8_t*       as3p;

// ---------------- prepass: dequantize weights -> bf16, layout [co][kc][cil] ----------------
__global__ __launch_bounds__(256) void dequant_weights(
    const int* __restrict__ widx, const float* __restrict__ lut,
    uint16_t* __restrict__ Bw) {
  int idx = blockIdx.x * 256 + threadIdx.x;        // < 256*36*64 = 589824
  int co  = idx / (KCTOT * BK);
  int r   = idx - co * (KCTOT * BK);
  int kc  = r >> 6;
  int cil = r & 63;
  int cc  = kc / 9;
  int tap = kc - cc * 9;
  int ci  = cc * 64 + cil;
  int wv  = widx[(co * CCH + ci) * 9 + tap];
  uint32_t b  = __float_as_uint(lut[wv]);
  uint32_t rn = (b + 0x7fffu + ((b >> 16) & 1u)) >> 16;   // RN-even to bf16
  Bw[idx] = (uint16_t)rn;
}

// ---------------- main: BM=256 x BN=128, 512 threads, 1 barrier/tap ----------------
// A: 372-row halo (row r holds m-row m0+r-58; row 371 = zeros), 128 B stride,
//    granule XOR-swizzle pos = (grp ^ (row&7)) -> conflict-free reads.
// B: 2 x 16 KB double buffer, staged by global_load_lds (2 ops/thread), granule
//    source pre-swizzled ck = g ^ (co&7). Stage for tap t+1 issued AFTER tap t's
//    barrier -> stays in flight the whole tap; vmcnt(0) at tap top waits only it.
__global__ __launch_bounds__(512, 4) void conv_mfma(
    const float* __restrict__ in, const uint16_t* __restrict__ Bw,
    const float* __restrict__ bias, float* __restrict__ out) {

  __shared__ __align__(16) uint16_t A_lds[372 * 64];      // 47.6 KB
  __shared__ __align__(16) uint16_t B_lds[2 * 128 * 64];  // 32 KB   (total 80.4 KB)

  const int t    = threadIdx.x;
  const int lane = t & 63;
  const int wv   = t >> 6;          // wave 0..7
  const int wm   = wv & 3;          // m-tile 0..3 (64 rows each)
  const int wn   = wv >> 2;         // n-tile 0..1 (64 cols each)
  const int lrow = lane & 15;
  const int kgrp = lane >> 4;       // 0..3

  const int m0  = blockIdx.x * 256;
  const int co0 = blockIdx.y * 128;

  // B staging constants: wave wv stages co rows [wv*16, wv*16+16)
  const int b_row8 = lane >> 3;     // 0..7
  const int b_g    = lane & 7;      // dest granule position

  // ---- issue B stage for kc=0 into buf0 (overlaps first A gather) ----
#pragma unroll
  for (int c = 0; c < 2; ++c) {
    const int co_l = wv * 16 + c * 8 + b_row8;
    const int ck   = b_g ^ (co_l & 7);
    const uint8_t* gsrc = (const uint8_t*)(Bw + ((size_t)(co0 + co_l) * KCTOT) * BK) + ck * 16;
    as3p ldst = (as3p)((uint8_t*)B_lds + (wv * 16 + c * 8) * 128);
    __builtin_amdgcn_global_load_lds((as1cp)gsrc, ldst, 16, 0, 0);
  }

  // per-lane masks / row bases for the 4 m-subtiles
  int hh[4], ww[4], rbase[4];
#pragma unroll
  for (int mi = 0; mi < 4; ++mi) {
    const int m = m0 + wm * 64 + mi * 16 + lrow;
    const int n = m / HW;
    const int s = m - n * HW;
    hh[mi] = s / WDIM;
    ww[mi] = s - hh[mi] * WDIM;
    rbase[mi] = wm * 64 + mi * 16 + lrow + 58;   // A row index before tap shift
  }

  f32x4 acc[4][4];
#pragma unroll
  for (int i = 0; i < 4; ++i)
#pragma unroll
    for (int j = 0; j < 4; ++j)
      acc[i][j] = (f32x4){0.f, 0.f, 0.f, 0.f};

#pragma unroll 1
  for (int cc = 0; cc < 4; ++cc) {
    if (cc) {  // all waves must be done reading A_lds before overwrite
      __builtin_amdgcn_sched_barrier(0);
      __builtin_amdgcn_s_barrier();
      __builtin_amdgcn_sched_barrier(0);
    }

    // ---- stage A halo: rows r = lane + 64*i (coalesced), channel-group = wv ----
#pragma unroll
    for (int i = 0; i < 6; ++i) {
      const int r = lane + 64 * i;
      if (r < 372) {
        u32x4 pk = (u32x4){0u, 0u, 0u, 0u};
        if (r != 371) {                          // row 371 stays zeros
          long g = (long)m0 + r - 58;
          g = g < 0 ? 0 : (g >= MTOT ? (MTOT - 1) : g);  // clamped rows masked at use
          const int n = (int)((unsigned long)g / HW);
          const int s = (int)(g - (long)n * HW);
          const float* p = in + (size_t)n * (CCH * HW) + (size_t)(cc * 64 + wv * 8) * HW + s;
#pragma unroll
          for (int jj = 0; jj < 4; ++jj) {
            const uint32_t b0 = __float_as_uint(p[(size_t)(2 * jj) * HW]);
            const uint32_t b1 = __float_as_uint(p[(size_t)(2 * jj + 1) * HW]);
            pk[jj] = (b0 >> 16) | (b1 & 0xffff0000u);
          }
        }
        *(u32x4*)((uint8_t*)A_lds + r * 128 + ((wv ^ (r & 7)) << 4)) = pk;
      }
    }
    asm volatile("s_waitcnt lgkmcnt(0)" ::: "memory");
    __builtin_amdgcn_sched_barrier(0);
    __builtin_amdgcn_s_barrier();
    __builtin_amdgcn_sched_barrier(0);

    const int scc = (cc & 1) << 14;

#pragma unroll
    for (int tap = 0; tap < 9; ++tap) {
      const int kc      = cc * 9 + tap;
      const int rdoff   = scc ^ ((tap & 1) << 14);   // buf[kc&1]
      const int wroff   = rdoff ^ 16384;
      const int kc_next = (tap == 8 && cc == 3) ? 35 : kc + 1;   // dummy at very end

      // ---- single barrier per tap: my stage(kc) done, then all waves' visible ----
      asm volatile("s_waitcnt vmcnt(0)" ::: "memory");
      __builtin_amdgcn_sched_barrier(0);
      __builtin_amdgcn_s_barrier();
      __builtin_amdgcn_sched_barrier(0);

      // ---- issue stage(kc_next) -> R(t+1); in flight across this whole tap ----
#pragma unroll
      for (int c = 0; c < 2; ++c) {
        const int co_l = wv * 16 + c * 8 + b_row8;
        const int ck   = b_g ^ (co_l & 7);
        const uint8_t* gsrc =
            (const uint8_t*)(Bw + ((size_t)(co0 + co_l) * KCTOT + kc_next) * BK) + ck * 16;
        as3p ldst = (as3p)((uint8_t*)B_lds + wroff + (wv * 16 + c * 8) * 128);
        __builtin_amdgcn_global_load_lds((as1cp)gsrc, ldst, 16, 0, 0);
      }

      const int kh = tap / 3;
      const int dh = kh - 1;
      const int dw = (tap - kh * 3) - 1;
      const int d  = dh * WDIM + dw;

      // ---- ks=0: frags + 16 MFMA ----
      bf16x8 a0[4], b0[4];
#pragma unroll
      for (int mi = 0; mi < 4; ++mi) {
        const bool valid = (((unsigned)(hh[mi] + dh)) < 56u) & (((unsigned)(ww[mi] + dw)) < 56u);
        const int row = rbase[mi] + d;
        const int ad  = valid ? (row * 128 + ((kgrp ^ (row & 7)) << 4))
                              : (371 * 128 + (kgrp << 4));
        a0[mi] = *(const bf16x8*)((const uint8_t*)A_lds + ad);
      }
#pragma unroll
      for (int ni = 0; ni < 4; ++ni) {
        const int nrow = wn * 64 + ni * 16 + lrow;
        b0[ni] = *(const bf16x8*)((const uint8_t*)B_lds + rdoff + nrow * 128 +
                                  ((kgrp ^ (lrow & 7)) << 4));
      }
      __builtin_amdgcn_s_setprio(1);
#pragma unroll
      for (int mi = 0; mi < 4; ++mi)
#pragma unroll
        for (int ni = 0; ni < 4; ++ni)
          acc[mi][ni] = __builtin_amdgcn_mfma_f32_16x16x32_bf16(
              a0[mi], b0[ni], acc[mi][ni], 0, 0, 0);
      __builtin_amdgcn_s_setprio(0);

      // ---- ks=1: frags + 16 MFMA ----
      bf16x8 a1[4], b1[4];
#pragma unroll
      for (int mi = 0; mi < 4; ++mi) {
        const bool valid = (((unsigned)(hh[mi] + dh)) < 56u) & (((unsigned)(ww[mi] + dw)) < 56u);
        const int row = rbase[mi] + d;
        const int ad  = valid ? (row * 128 + (((4 + kgrp) ^ (row & 7)) << 4))
                              : (371 * 128 + ((4 + kgrp) << 4));
        a1[mi] = *(const bf16x8*)((const uint8_t*)A_lds + ad);
      }
#pragma unroll
      for (int ni = 0; ni < 4; ++ni) {
        const int nrow = wn * 64 + ni * 16 + lrow;
        b1[ni] = *(const bf16x8*)((const uint8_t*)B_lds + rdoff + nrow * 128 +
                                  (((4 + kgrp) ^ (lrow & 7)) << 4));
      }
      __builtin_amdgcn_s_setprio(1);
#pragma unroll
      for (int mi = 0; mi < 4; ++mi)
#pragma unroll
        for (int ni = 0; ni < 4; ++ni)
          acc[mi][ni] = __builtin_amdgcn_mfma_f32_16x16x32_bf16(
              a1[mi], b1[ni], acc[mi][ni], 0, 0, 0);
      __builtin_amdgcn_s_setprio(0);
    }
  }

  // ---- epilogue: add bias, store (D: row=(lane>>4)*4+r, col=lane&15) ----
  float bv[4];
#pragma unroll
  for (int ni = 0; ni < 4; ++ni)
    bv[ni] = bias[co0 + wn * 64 + ni * 16 + lrow];

#pragma unroll
  for (int mi = 0; mi < 4; ++mi) {
#pragma unroll
    for (int r = 0; r < 4; ++r) {
      const int mrow = m0 + wm * 64 + mi * 16 + kgrp * 4 + r;
      const int ni_img = mrow / HW;
      const int ss = mrow - ni_img * HW;
      float* ob = out + (size_t)ni_img * (CCH * HW) + ss;
#pragma unroll
      for (int ni = 0; ni < 4; ++ni) {
        const int co = co0 + wn * 64 + ni * 16 + lrow;
        ob[(size_t)co * HW] = acc[mi][ni][r] + bv[ni];
      }
    }
  }
}

extern "C" void kernel_launch(void* const* d_in, const int* in_sizes, int n_in,
                              void* d_out, int out_size, void* d_ws, size_t ws_size,
                              hipStream_t stream) {
  const float* in   = (const float*)d_in[0];
  const int*   widx = (const int*)d_in[1];
  const float* lut  = (const float*)d_in[2];
  const float* bias = (const float*)d_in[3];
  float* out = (float*)d_out;
  uint16_t* Bw = (uint16_t*)d_ws;   // 589824 * 2 B = 1.18 MB scratch

  dequant_weights<<<dim3(589824 / 256), dim3(256), 0, stream>>>(widx, lut, Bw);
  conv_mfma<<<dim3(MTOT / 256, CCH / 128), dim3(512), 0, stream>>>(in, Bw, bias, out);
}

// Round 5
// 342.604 us; speedup vs baseline: 1.6537x; 1.6537x over previous
//
#include <hip/hip_runtime.h>
#include <stdint.h>

// Problem constants
#define NIMG   32
#define CCH    256
#define WDIM   56
#define HW     3136          // 56*56
#define MTOT   (NIMG*HW)     // 100352
#define KCTOT  36            // 4 ci-chunks * 9 taps
#define AROWS  244           // A halo rows: r = m-m0+58 in [1,242]; row 243 = zeros
#define AGB    (AROWS*16)    // bytes per A granule-plane = 3904

typedef __attribute__((ext_vector_type(8))) short    bf16x8;
typedef __attribute__((ext_vector_type(4))) float    f32x4;
typedef __attribute__((ext_vector_type(4))) uint32_t u32x4;

typedef __attribute__((address_space(1))) const uint8_t* as1cp;
typedef __attribute__((address_space(3))) uint8_t*       as3p;

// ---------------- prepass: dequantize -> bf16, TRANSPOSED layout [kc][g][co][e] ----------------
// Bw2 element idx = ((kc*8 + g)*256 + co)*8 + e, holding lut[widx[co][cc*64+g*8+e][tap]]
// -> B staging reads become fully contiguous 1 KB runs per global_load_lds set.
__global__ __launch_bounds__(256) void dequant_weights(
    const int* __restrict__ widx, const float* __restrict__ lut,
    uint16_t* __restrict__ Bw2) {
  int idx = blockIdx.x * 256 + threadIdx.x;       // < 589824
  int e   = idx & 7;
  int co  = (idx >> 3) & 255;
  int gk  = idx >> 11;            // kc*8 + g
  int kc  = gk >> 3;
  int g   = gk & 7;
  int cc  = kc / 9;
  int tap = kc - cc * 9;
  int ci  = cc * 64 + g * 8 + e;
  int wv  = widx[(co * CCH + ci) * 9 + tap];
  uint32_t b  = __float_as_uint(lut[wv]);
  uint32_t rn = (b + 0x7fffu + ((b >> 16) & 1u)) >> 16;   // RN-even to bf16
  Bw2[idx] = (uint16_t)rn;
}

// ---------------- main: BM=128 x BN=128, 256 threads, 1 barrier/tap, conflict-free LDS ----------------
// A_lds: [g][row] planes (g = k-octet 0..7), row stride 16 B -> consecutive-lane reads/writes.
// B_lds: 2 x [g][co] 16 KB buffers, staged by 4 global_load_lds/thread from transposed Bw2.
// Per tap: vmcnt(0) (waits only last tap's stage) -> s_barrier -> issue stage(t+1) ->
// ds_read frags -> 32 MFMA. vmcnt never counts anything but the 4 in-flight stage ops.
__global__ __launch_bounds__(256, 2) void conv_mfma(
    const float* __restrict__ in, const uint16_t* __restrict__ Bw2,
    const float* __restrict__ bias, float* __restrict__ out) {

  __shared__ __align__(16) uint16_t A_lds[8 * AROWS * 8];   // 31232 B
  __shared__ __align__(16) uint16_t B_lds[2 * 8 * 128 * 8]; // 32768 B  (total 64 KB)

  const int t    = threadIdx.x;
  const int lane = t & 63;
  const int wv   = t >> 6;          // wave 0..3
  const int wm   = wv & 1;          // m-tile 0..1 (64 rows)
  const int wn   = wv >> 1;         // n-tile 0..1 (64 cols)
  const int lrow = lane & 15;
  const int kgrp = lane >> 4;       // 0..3

  // XCD-chunked swizzle: 1568 blocks, 8 XCDs, 196 blocks/XCD; consecutive nid = adjacent m-tiles
  const int bid = blockIdx.x + gridDim.x * blockIdx.y;
  const int nid = (bid & 7) * 196 + (bid >> 3);
  const int m0  = (nid % 784) * 128;
  const int co0 = (nid / 784) * 128;

  // ---- issue B stage for kc=0 into buf0 (overlaps first A gather) ----
#pragma unroll
  for (int c = 0; c < 4; ++c) {
    const int gid = c * 256 + t;                  // granule id: g = gid>>7, co = gid&127
    const uint8_t* gsrc = (const uint8_t*)Bw2 +
        ((size_t)(gid >> 7) << 12) + (size_t)(co0 + (gid & 127)) * 16;   // kc=0
    as3p ldst = (as3p)((uint8_t*)B_lds + (c * 256 + wv * 64) * 16);
    __builtin_amdgcn_global_load_lds(gsrc, ldst, 16, 0, 0);
  }

  // zero row (row 243 of each granule plane)
  if (t < 8) *(u32x4*)((uint8_t*)A_lds + t * AGB + 243 * 16) = (u32x4){0u, 0u, 0u, 0u};

  // per-lane masks / A row bases for the 4 m-subtiles
  int hh[4], ww[4], rbase[4];
#pragma unroll
  for (int mi = 0; mi < 4; ++mi) {
    const int m = m0 + wm * 64 + mi * 16 + lrow;
    const int n = m / HW;
    const int s = m - n * HW;
    hh[mi] = s / WDIM;
    ww[mi] = s - hh[mi] * WDIM;
    rbase[mi] = wm * 64 + mi * 16 + lrow + 58;
  }

  f32x4 acc[4][4];
#pragma unroll
  for (int i = 0; i < 4; ++i)
#pragma unroll
    for (int j = 0; j < 4; ++j)
      acc[i][j] = (f32x4){0.f, 0.f, 0.f, 0.f};

#pragma unroll 1
  for (int cc = 0; cc < 4; ++cc) {
    if (cc) {  // all waves done reading A_lds before overwrite
      __builtin_amdgcn_sched_barrier(0);
      __builtin_amdgcn_s_barrier();
      __builtin_amdgcn_sched_barrier(0);
    }

    // ---- stage A halo: [g][row] planes; lanes write consecutive rows -> conflict-free ----
#pragma unroll
    for (int i = 0; i < 8; ++i) {
      const int r = (t & 31) + 32 * i;            // 0..255
      if (r <= 242) {
        const int g = t >> 5;                     // 0..7 channel-octet
        long gm = (long)m0 + r - 58;
        gm = gm < 0 ? 0 : (gm >= MTOT ? (MTOT - 1) : gm);   // clamped rows masked at use
        const int n = (int)((unsigned long)gm / HW);
        const int s = (int)(gm - (long)n * HW);
        const float* p = in + (size_t)n * (CCH * HW) + (size_t)(cc * 64 + g * 8) * HW + s;
        u32x4 pk;
#pragma unroll
        for (int jj = 0; jj < 4; ++jj) {
          const uint32_t b0 = __float_as_uint(p[(size_t)(2 * jj) * HW]);
          const uint32_t b1 = __float_as_uint(p[(size_t)(2 * jj + 1) * HW]);
          pk[jj] = (b0 >> 16) | (b1 & 0xffff0000u);
        }
        *(u32x4*)((uint8_t*)A_lds + g * AGB + r * 16) = pk;
      }
    }
    asm volatile("s_waitcnt lgkmcnt(0)" ::: "memory");
    __builtin_amdgcn_sched_barrier(0);
    __builtin_amdgcn_s_barrier();
    __builtin_amdgcn_sched_barrier(0);

#pragma unroll
    for (int tap = 0; tap < 9; ++tap) {
      const int kc    = cc * 9 + tap;
      const int rdoff = (kc & 1) << 14;           // buf[kc&1]
      const int wroff = rdoff ^ (1 << 14);
      const int kcn   = (kc < 35) ? kc + 1 : 35;  // dummy re-stage at the very end

      // ---- single sync point: my stage(kc) landed, then everyone's visible ----
      asm volatile("s_waitcnt vmcnt(0)" ::: "memory");
      __builtin_amdgcn_sched_barrier(0);
      __builtin_amdgcn_s_barrier();
      __builtin_amdgcn_sched_barrier(0);

      // ---- issue stage(kcn): 4 x 1 KB contiguous global_load_lds, in flight all tap ----
#pragma unroll
      for (int c = 0; c < 4; ++c) {
        const int gid = c * 256 + t;
        const uint8_t* gsrc = (const uint8_t*)Bw2 + (size_t)kcn * 32768 +
            ((size_t)(gid >> 7) << 12) + (size_t)(co0 + (gid & 127)) * 16;
        as3p ldst = (as3p)((uint8_t*)B_lds + wroff + (c * 256 + wv * 64) * 16);
        __builtin_amdgcn_global_load_lds(gsrc, ldst, 16, 0, 0);
      }

      const int kh = tap / 3;
      const int dh = kh - 1;
      const int dw = (tap - kh * 3) - 1;
      const int d  = dh * WDIM + dw;

      // ---- frag reads: all consecutive-lane b128, conflict-free ----
      bf16x8 af[2][4], bfb[2][4];
#pragma unroll
      for (int mi = 0; mi < 4; ++mi) {
        const bool valid = (((unsigned)(hh[mi] + dh)) < 56u) & (((unsigned)(ww[mi] + dw)) < 56u);
        const int r = valid ? (rbase[mi] + d) : 243;
#pragma unroll
        for (int ks = 0; ks < 2; ++ks)
          af[ks][mi] = *(const bf16x8*)((const uint8_t*)A_lds + (ks * 4 + kgrp) * AGB + r * 16);
      }
#pragma unroll
      for (int ks = 0; ks < 2; ++ks)
#pragma unroll
        for (int ni = 0; ni < 4; ++ni) {
          const int col = wn * 64 + ni * 16 + lrow;
          bfb[ks][ni] = *(const bf16x8*)((const uint8_t*)B_lds + rdoff +
                                         (ks * 4 + kgrp) * 2048 + col * 16);
        }

      __builtin_amdgcn_s_setprio(1);
#pragma unroll
      for (int ks = 0; ks < 2; ++ks)
#pragma unroll
        for (int mi = 0; mi < 4; ++mi)
#pragma unroll
          for (int ni = 0; ni < 4; ++ni)
            acc[mi][ni] = __builtin_amdgcn_mfma_f32_16x16x32_bf16(
                af[ks][mi], bfb[ks][ni], acc[mi][ni], 0, 0, 0);
      __builtin_amdgcn_s_setprio(0);
    }
  }

  // ---- epilogue: add bias, store (D: row=(lane>>4)*4+r, col=lane&15) ----
  float bv[4];
#pragma unroll
  for (int ni = 0; ni < 4; ++ni)
    bv[ni] = bias[co0 + wn * 64 + ni * 16 + lrow];

#pragma unroll
  for (int mi = 0; mi < 4; ++mi) {
#pragma unroll
    for (int r = 0; r < 4; ++r) {
      const int mrow = m0 + wm * 64 + mi * 16 + kgrp * 4 + r;
      const int ni_img = mrow / HW;
      const int ss = mrow - ni_img * HW;
      float* ob = out + (size_t)ni_img * (CCH * HW) + ss;
#pragma unroll
      for (int ni = 0; ni < 4; ++ni) {
        const int co = co0 + wn * 64 + ni * 16 + lrow;
        ob[(size_t)co * HW] = acc[mi][ni][r] + bv[ni];
      }
    }
  }
}

extern "C" void kernel_launch(void* const* d_in, const int* in_sizes, int n_in,
                              void* d_out, int out_size, void* d_ws, size_t ws_size,
                              hipStream_t stream) {
  const float* in   = (const float*)d_in[0];
  const int*   widx = (const int*)d_in[1];
  const float* lut  = (const float*)d_in[2];
  const float* bias = (const float*)d_in[3];
  float* out = (float*)d_out;
  uint16_t* Bw2 = (uint16_t*)d_ws;   // 589824 * 2 B = 1.18 MB scratch

  dequant_weights<<<dim3(589824 / 256), dim3(256), 0, stream>>>(widx, lut, Bw2);
  conv_mfma<<<dim3(MTOT / 128, CCH / 128), dim3(256), 0, stream>>>(in, Bw2, bias, out);
}